// Round 22
// baseline (106.853 us; speedup 1.0000x reference)
//
#include <hip/hip_runtime.h>

#define NNODES 50000
#define NEDGES 800000
#define IN_C   512
#define HID_C  128
#define OUT_C  64
#define NBUCK  196        // bucket = dest >> 8
#define BCAP   5120       // fixed bucket capacity (mean 4096, sigma 64 -> +16 sigma)
#define BREG   5376       // padded CSR region per bucket (BCAP + 256 self-loops)

typedef float  f32x4  __attribute__((ext_vector_type(4)));
typedef __bf16 bf16x8 __attribute__((ext_vector_type(8)));
typedef short  short8 __attribute__((ext_vector_type(8)));

#define GLDS(src, dst) \
  __builtin_amdgcn_global_load_lds( \
      (const __attribute__((address_space(1))) unsigned int*)(src), \
      (__attribute__((address_space(3))) unsigned int*)(dst), 16, 0, 0)

__device__ __forceinline__ float bf2f(unsigned short u) {
  unsigned int x = (unsigned int)u << 16;
  return __builtin_bit_cast(float, x);
}
__device__ __forceinline__ unsigned short f16bits(float f) {
  _Float16 h = (_Float16)f;
  return __builtin_bit_cast(unsigned short, h);
}
__device__ __forceinline__ float f16val(unsigned short u) {
  return (float)__builtin_bit_cast(_Float16, u);
}

// ---------------- prep0: seed claim cursors + split/transpose W1,W2 ----------------

__device__ __forceinline__ void wsplit_one(const float* __restrict__ W,
                                           unsigned short* __restrict__ Th,
                                           unsigned short* __restrict__ Tl,
                                           int K, int N, int id) {
  int k = id % K, n = id / K;           // consecutive id -> consecutive k (coalesced writes)
  float f = W[(size_t)k * N + n];
  __bf16 hb = (__bf16)f;
  __bf16 lb = (__bf16)(f - (float)hb);
  Th[id] = __builtin_bit_cast(unsigned short, hb);
  Tl[id] = __builtin_bit_cast(unsigned short, lb);
}

__global__ void __launch_bounds__(256) prep0_kernel(
    unsigned int* __restrict__ gclaim,
    const float* __restrict__ W1, unsigned short* __restrict__ W1th,
    unsigned short* __restrict__ W1tl,
    const float* __restrict__ W2, unsigned short* __restrict__ W2th,
    unsigned short* __restrict__ W2tl) {
  int id = blockIdx.x * blockDim.x + threadIdx.x;
  if (id < 256) { if (id < NBUCK) gclaim[id] = (unsigned int)id * BCAP; return; }
  int s = id - 256;
  if (s < IN_C * HID_C) wsplit_one(W1, W1th, W1tl, IN_C, HID_C, s);
  else if (s < IN_C * HID_C + HID_C * OUT_C)
    wsplit_one(W2, W2th, W2tl, HID_C, OUT_C, s - IN_C * HID_C);
}

// ---------------- bin_scatter: standalone (98 blocks x 1024 thr, ~5us, full machine) ----
// Record u64: src:16 | dest_lo:8 | f16(ew):16. One returning atomic per (block,bin).
__global__ void __launch_bounds__(1024) bin_scatter_kernel(
    const int* __restrict__ ei, const float* __restrict__ ew,
    unsigned int* __restrict__ gclaim, unsigned long long* __restrict__ binned, int nE) {
  __shared__ unsigned int h[NBUCK];
  __shared__ unsigned int cur[NBUCK];
  int t = threadIdx.x;
  if (t < NBUCK) h[t] = 0;
  __syncthreads();
  int base = (int)blockIdx.x * 8192;
  int r[8]; unsigned int c[8]; unsigned short wb[8];
#pragma unroll
  for (int i = 0; i < 8; ++i) {
    int e = base + i * 1024 + t;
    if (e < nE) {
      r[i] = ei[e];
      c[i] = (unsigned int)ei[nE + e];
      wb[i] = f16bits(ew[e]);
      atomicAdd(&h[c[i] >> 8], 1u);
    } else {
      c[i] = 0xFFFFFFFFu;
    }
  }
  __syncthreads();
  if (t < NBUCK) cur[t] = h[t] ? atomicAdd(&gclaim[t], h[t]) : 0u;
  __syncthreads();
#pragma unroll
  for (int i = 0; i < 8; ++i) {
    if (c[i] != 0xFFFFFFFFu) {
      unsigned int pos = atomicAdd(&cur[c[i] >> 8], 1u);
      unsigned long long rec = (unsigned long long)((unsigned int)r[i] & 0xFFFFu)
                             | ((unsigned long long)(c[i] & 0xFFu) << 16)
                             | ((unsigned long long)wb[i] << 32);
      binned[pos] = rec;
    }
  }
}

// ---------------- gemm1 body: Y = bf16( X @ bf16(W1) ), split-A 2-term ----------------
// r20 form: 2-buffer dbuf LDS, one __syncthreads per K-chunk (r18/r19/r21: deeper or
// wider or counted-vmcnt all neutral-to-worse). smem = shared 48KB arena.
template <int K, int N, int WR, int WC>
__device__ __forceinline__ void gemm_body(char* smem, const float* __restrict__ X,
                                          const unsigned short* __restrict__ Bth,
                                          unsigned short* __restrict__ Y, int M, int bid) {
  constexpr int NW = WR * WC;
  constexpr int BM = WR * 32;
  constexpr int NI = K / 32;
  constexpr int ASLOTS = (BM / 8) / NW;    // 2
  constexpr int BSLOTS = (N / 16) / NW;    // 1

  float          (*As)[BM * 32] = reinterpret_cast<float(*)[BM * 32]>(smem);            // 2x16KB
  unsigned short (*Bs)[N * 32]  = reinterpret_cast<unsigned short(*)[N * 32]>(smem + 2 * BM * 32 * 4); // 2x8KB

  int tid = threadIdx.x;
  int lane = tid & 63, wid = tid >> 6;
  int wr = wid / WC, wc = wid % WC;
  int row0blk = bid * BM;
  int row0 = row0blk + wr * 32;
  int rlo = lane & 15;
  int khi = lane >> 4;

  f32x4 acc[2][4] = {};

  auto stage = [&](int t, int buf) {
    int kb = t * 32;
#pragma unroll
    for (int i = 0; i < ASLOTS; ++i) {
      int slot = wid * ASLOTS + i;
      int rt = slot * 8 + (lane >> 3);
      int gr = row0blk + rt; gr = gr < M ? gr : M - 1;
      int gs = (lane & 7) ^ (lane >> 3);
      GLDS(X + (size_t)gr * K + kb + gs * 4, &As[buf][slot * 256]);
    }
#pragma unroll
    for (int i = 0; i < BSLOTS; ++i) {
      int slot = wid * BSLOTS + i;
      int c = slot * 16 + (lane >> 2);
      int gs = (lane & 3) ^ (lane >> 4);
      GLDS(Bth + (size_t)c * K + kb + gs * 8, &Bs[buf][slot * 512]);
    }
  };

  stage(0, 0);
  __syncthreads();

#pragma unroll 1
  for (int t = 0; t < NI; ++t) {
    int buf = t & 1;
    if (t + 1 < NI) stage(t + 1, buf ^ 1);

    bf16x8 ah[2], al[2];
#pragma unroll
    for (int m = 0; m < 2; ++m) {
      int rt = wr * 32 + m * 16 + rlo;
      int p0 = (khi * 2) ^ (rlo & 7), p1 = (khi * 2 + 1) ^ (rlo & 7);
      f32x4 v0 = *reinterpret_cast<const f32x4*>(&As[buf][rt * 32 + p0 * 4]);
      f32x4 v1 = *reinterpret_cast<const f32x4*>(&As[buf][rt * 32 + p1 * 4]);
      float f[8] = {v0.x, v0.y, v0.z, v0.w, v1.x, v1.y, v1.z, v1.w};
#pragma unroll
      for (int i = 0; i < 8; ++i) {
        __bf16 hv = (__bf16)f[i];
        ah[m][i] = hv;
        al[m][i] = (__bf16)(f[i] - (float)hv);
      }
    }
    short8 bh[4];
#pragma unroll
    for (int n = 0; n < 4; ++n) {
      int c = wc * 64 + n * 16 + rlo;
      int pos = khi ^ (rlo >> 2);
      bh[n] = *reinterpret_cast<const short8*>(&Bs[buf][c * 32 + pos * 8]);
    }
#pragma unroll
    for (int m = 0; m < 2; ++m)
#pragma unroll
      for (int n = 0; n < 4; ++n)
        acc[m][n] = __builtin_amdgcn_mfma_f32_16x16x32_bf16(
            ah[m], __builtin_bit_cast(bf16x8, bh[n]), acc[m][n], 0, 0, 0);
#pragma unroll
    for (int m = 0; m < 2; ++m)
#pragma unroll
      for (int n = 0; n < 4; ++n)
        acc[m][n] = __builtin_amdgcn_mfma_f32_16x16x32_bf16(
            al[m], __builtin_bit_cast(bf16x8, bh[n]), acc[m][n], 0, 0, 0);
    __syncthreads();
  }

  // C/D: col = lane&15, row = (lane>>4)*4 + reg; store bf16 (RNE)
#pragma unroll
  for (int m = 0; m < 2; ++m)
#pragma unroll
    for (int j = 0; j < 4; ++j) {
      int row = row0 + m * 16 + khi * 4 + j;
      if (row < M) {
#pragma unroll
        for (int n = 0; n < 4; ++n) {
          __bf16 q = (__bf16)acc[m][n][j];
          Y[(size_t)row * N + wc * 64 + n * 16 + rlo] = __builtin_bit_cast(unsigned short, q);
        }
      }
    }
}

// ---------------- bucket_build branch: deg + CSR build (512 threads, shared arena) ------
__device__ __forceinline__ void build_body(char* smem,
    const unsigned long long* __restrict__ binned, const unsigned int* __restrict__ gclaim,
    float* __restrict__ dinv, int* __restrict__ offs, unsigned short* __restrict__ cnts,
    unsigned int* __restrict__ edges, int b) {
  unsigned int* ec    = (unsigned int*)smem;          // 1KB
  unsigned int* wf    = ec + 256;                     // 1KB
  unsigned int* cur   = wf + 256;                     // 1KB
  int*          sc    = (int*)(cur + 256);            // 1KB
  unsigned int* image = (unsigned int*)(sc + 256);    // 21KB  (total 25.6KB <= 48KB arena)

  int t = threadIdx.x;                                // 0..511
  int base = b * BCAP;
  int cnt = (int)gclaim[b] - base;
  int nb = min(256, NNODES - b * 256);
  int csrbase = b * BREG;

  if (t < 256) { ec[t] = 0; wf[t] = 0; }
  __syncthreads();
  for (int i = t; i < cnt; i += 512) {
    unsigned long long rec = binned[base + i];
    int dlo = (int)((rec >> 16) & 255ULL);
    atomicAdd(&ec[dlo], 1u);
    float w = f16val((unsigned short)(rec >> 32));
    atomicAdd(&wf[dlo], (unsigned int)(w * 1048576.0f + 0.5f));   // 2^20 fixed-point
  }
  __syncthreads();
  int cn = (t < nb) ? (int)ec[t] + 1 : 0;   // + self-loop slot
  if (t < 256) sc[t] = cn;
  __syncthreads();
  for (int off = 1; off < 256; off <<= 1) {
    int u = (t < 256 && t >= off) ? sc[t - off] : 0;
    __syncthreads();
    if (t < 256) sc[t] += u;
    __syncthreads();
  }
  if (t < nb) {
    float deg = (float)wf[t] * (1.0f / 1048576.0f) + 1.0f;   // + self-loop w=1
    int g = b * 256 + t;
    float di = rsqrtf(deg);
    dinv[g] = di;
    int loc = sc[t] - cn;
    offs[g] = csrbase + loc;
    cnts[g] = (unsigned short)ec[t];
    cur[t] = (unsigned int)(loc + 1);
    image[loc] = (unsigned int)g | (0x3C00u << 16);   // self-loop, w = f16(1.0)
  }
  __syncthreads();
  for (int i = t; i < cnt; i += 512) {
    unsigned long long rec = binned[base + i];
    int src = (int)(rec & 0xFFFFULL);
    int dlo = (int)((rec >> 16) & 255ULL);
    unsigned int wb = (unsigned int)((rec >> 32) & 0xFFFFULL);
    unsigned int pos = atomicAdd(&cur[dlo], 1u);
    image[pos] = (unsigned int)src | (wb << 16);
  }
  __syncthreads();
  int total = cnt + nb;
  for (int j = t; j < total; j += 512) edges[csrbase + j] = image[j];
}

// ---------------- fused: bucket_build (blocks [0,NBUCK)) ∥ gemm1 (rest) ----------------
// Both depend only on completed scatter / (x, W1h) respectively -> true overlap: the
// ~10us build hides under the ~50us gemm. 48KB shared arena reused by both branches.
__global__ void __launch_bounds__(512, 4) fused_build_gemm1_kernel(
    const float* __restrict__ X, const unsigned short* __restrict__ Bth,
    unsigned short* __restrict__ Y, int M,
    const unsigned long long* __restrict__ binned, const unsigned int* __restrict__ gclaim,
    float* __restrict__ dinv, int* __restrict__ offs, unsigned short* __restrict__ cnts,
    unsigned int* __restrict__ edges) {
  __shared__ char smem[49152];
  if ((int)blockIdx.x < NBUCK)
    build_body(smem, binned, gclaim, dinv, offs, cnts, edges, (int)blockIdx.x);
  else
    gemm_body<IN_C, HID_C, 4, 2>(smem, X, Bth, Y, M, (int)blockIdx.x - NBUCK);
}

// ---------------- bf16-A MFMA GEMM (layer 2): A bf16, 2 terms (Wh + Wl) ----------------
template <int K, int N, int WR, int WC>
__global__ void __launch_bounds__(WR * WC * 64, 4) gemm_bf16a_kernel(
    const unsigned short* __restrict__ X, const unsigned short* __restrict__ Bth,
    const unsigned short* __restrict__ Btl, unsigned short* __restrict__ Y, int M) {
  constexpr int NW = WR * WC;
  constexpr int BM = WR * 32;
  constexpr int NI = K / 32;
  constexpr int ASLOTS = (BM / 16) / NW;
  constexpr int BSLOTS = (N / 8) / NW;

  __shared__ unsigned short As[2][BM * 32];
  __shared__ unsigned short Bs[2][2][N * 32];

  int tid = threadIdx.x;
  int lane = tid & 63, wid = tid >> 6;
  int wr = wid / WC, wc = wid % WC;
  int row0blk = blockIdx.x * BM;
  int row0 = row0blk + wr * 32;
  int rlo = lane & 15;
  int khi = lane >> 4;

  f32x4 acc[2][4] = {};

  auto stage = [&](int t, int buf) {
    int kb = t * 32;
#pragma unroll
    for (int i = 0; i < ASLOTS; ++i) {
      int slot = wid * ASLOTS + i;
      int rt = slot * 16 + (lane >> 2);
      int gr = row0blk + rt; gr = gr < M ? gr : M - 1;
      int gs = (lane & 3) ^ ((lane >> 3) & 3);
      GLDS(X + (size_t)gr * K + kb + gs * 8, &As[buf][slot * 512]);
    }
#pragma unroll
    for (int i = 0; i < BSLOTS; ++i) {
      int slot = wid * BSLOTS + i;
      int half = slot / (N / 16);
      int idx = slot % (N / 16);
      const unsigned short* Wt = half ? Btl : Bth;
      int c = idx * 16 + (lane >> 2);
      int gs = (lane & 3) ^ (lane >> 4);
      GLDS(Wt + (size_t)c * K + kb + gs * 8, &Bs[buf][half][idx * 512]);
    }
  };

  stage(0, 0);
  __syncthreads();

#pragma unroll 1
  for (int t = 0; t < NI; ++t) {
    int buf = t & 1;
    if (t + 1 < NI) stage(t + 1, buf ^ 1);

    short8 ah[2];
#pragma unroll
    for (int m = 0; m < 2; ++m) {
      int rt = wr * 32 + m * 16 + rlo;
      int g = khi ^ ((rt >> 1) & 3);
      ah[m] = *reinterpret_cast<const short8*>(&As[buf][rt * 32 + g * 8]);
    }
    short8 bh[4], bl[4];
#pragma unroll
    for (int n = 0; n < 4; ++n) {
      int c = wc * 64 + n * 16 + rlo;
      int pos = khi ^ (rlo >> 2);
      bh[n] = *reinterpret_cast<const short8*>(&Bs[buf][0][c * 32 + pos * 8]);
      bl[n] = *reinterpret_cast<const short8*>(&Bs[buf][1][c * 32 + pos * 8]);
    }
#pragma unroll
    for (int m = 0; m < 2; ++m)
#pragma unroll
      for (int n = 0; n < 4; ++n)
        acc[m][n] = __builtin_amdgcn_mfma_f32_16x16x32_bf16(
            __builtin_bit_cast(bf16x8, ah[m]), __builtin_bit_cast(bf16x8, bh[n]),
            acc[m][n], 0, 0, 0);
#pragma unroll
    for (int m = 0; m < 2; ++m)
#pragma unroll
      for (int n = 0; n < 4; ++n)
        acc[m][n] = __builtin_amdgcn_mfma_f32_16x16x32_bf16(
            __builtin_bit_cast(bf16x8, ah[m]), __builtin_bit_cast(bf16x8, bl[n]),
            acc[m][n], 0, 0, 0);
    __syncthreads();
  }

#pragma unroll
  for (int m = 0; m < 2; ++m)
#pragma unroll
    for (int j = 0; j < 4; ++j) {
      int row = row0 + m * 16 + khi * 4 + j;
      if (row < M) {
#pragma unroll
        for (int n = 0; n < 4; ++n) {
          __bf16 q = (__bf16)acc[m][n][j];
          Y[(size_t)row * N + wc * 64 + n * 16 + rlo] = __builtin_bit_cast(unsigned short, q);
        }
      }
    }
}

// ---------------- CSR aggregation over bf16 features (dinv-folded) ----------------
template <int F, bool RELU, bool OUTBF>
__global__ void __launch_bounds__(256) agg_kernel(const unsigned short* __restrict__ feat,
                                                  const int* __restrict__ offs,
                                                  const unsigned short* __restrict__ cnts,
                                                  const unsigned int* __restrict__ edges,
                                                  const float* __restrict__ dinv,
                                                  const float* __restrict__ bias,
                                                  void* __restrict__ outv, int n) {
  constexpr int LPN = F / 8;
  constexpr int NPW = 64 / LPN;
  constexpr int NPB = 4 * NPW;
  int wid = threadIdx.x >> 6;
  int lane = threadIdx.x & 63;
  int node = blockIdx.x * NPB + wid * NPW + lane / LPN;
  int lf = (lane % LPN) * 8;
  if (node >= n) return;
  int e0 = offs[node];
  int e1 = e0 + 1 + (int)cnts[node];

  float acc[8] = {};

  auto fmaEdge = [&](unsigned int q) {
    int row = (int)(q & 0xFFFFu);
    float w = f16val((unsigned short)(q >> 16)) * dinv[row];
    short8 v = *reinterpret_cast<const short8*>(&feat[(size_t)row * F + lf]);
#pragma unroll
    for (int j = 0; j < 8; ++j)
      acc[j] = fmaf(w, bf2f((unsigned short)v[j]), acc[j]);
  };

  int e = e0;
  for (; e + 4 <= e1; e += 4) {
    unsigned int q0 = edges[e], q1 = edges[e + 1], q2 = edges[e + 2], q3 = edges[e + 3];
    fmaEdge(q0); fmaEdge(q1); fmaEdge(q2); fmaEdge(q3);
  }
  for (; e < e1; ++e) fmaEdge(edges[e]);

  float dd = dinv[node];
#pragma unroll
  for (int j = 0; j < 8; ++j) {
    acc[j] = fmaf(acc[j], dd, bias[lf + j]);
    if (RELU) acc[j] = fmaxf(acc[j], 0.f);
  }
  if constexpr (OUTBF) {
    short8 o;
#pragma unroll
    for (int j = 0; j < 8; ++j) {
      __bf16 q = (__bf16)acc[j];
      o[j] = (short)__builtin_bit_cast(unsigned short, q);
    }
    *reinterpret_cast<short8*>((unsigned short*)outv + (size_t)node * F + lf) = o;
  } else {
    float* out = (float*)outv;
    float4 o0 = make_float4(acc[0], acc[1], acc[2], acc[3]);
    float4 o1 = make_float4(acc[4], acc[5], acc[6], acc[7]);
    *reinterpret_cast<float4*>(&out[(size_t)node * F + lf]) = o0;
    *reinterpret_cast<float4*>(&out[(size_t)node * F + lf + 4]) = o1;
  }
}

// ---------------- launch ----------------

extern "C" void kernel_launch(void* const* d_in, const int* in_sizes, int n_in,
                              void* d_out, int out_size, void* d_ws, size_t ws_size,
                              hipStream_t stream) {
  const float* x  = (const float*)d_in[0];
  const int*   ei = (const int*)d_in[1];     // [2, E] int
  const float* ew = (const float*)d_in[2];
  const float* W1 = (const float*)d_in[3];
  const float* b1 = (const float*)d_in[4];
  const float* W2 = (const float*)d_in[5];
  const float* b2 = (const float*)d_in[6];
  float* out = (float*)d_out;

  const int N = NNODES, E = NEDGES;

  char* p = (char*)d_ws;
  auto alloc = [&](size_t bytes) { char* r = p; p += (bytes + 255) & ~(size_t)255; return r; };
  unsigned int* gclaim = (unsigned int*)alloc(256 * 4);
  float* dinv   = (float*)alloc((size_t)N * 4);
  int*   offs   = (int*)  alloc((size_t)N * 4);
  unsigned short* cnts = (unsigned short*)alloc((size_t)N * 2);
  unsigned long long* binned = (unsigned long long*)alloc((size_t)NBUCK * BCAP * 8);
  unsigned int* edges  = (unsigned int*)alloc((size_t)NBUCK * BREG * 4);
  unsigned short* xw = (unsigned short*)alloc((size_t)N * HID_C * 2); // bf16 pre-agg / h2
  unsigned short* h  = (unsigned short*)alloc((size_t)N * HID_C * 2); // bf16 layer-1 out
  unsigned short* W1th = (unsigned short*)alloc((size_t)IN_C * HID_C * 2);
  unsigned short* W1tl = (unsigned short*)alloc((size_t)IN_C * HID_C * 2);
  unsigned short* W2th = (unsigned short*)alloc((size_t)HID_C * OUT_C * 2);
  unsigned short* W2tl = (unsigned short*)alloc((size_t)HID_C * OUT_C * 2);

  // prep0: seed gclaim (bucket cursors) + wsplit W1,W2
  const int PREP0 = 256 + IN_C * HID_C + HID_C * OUT_C;
  prep0_kernel<<<(PREP0 + 255) / 256, 256, 0, stream>>>(
      gclaim, W1, W1th, W1tl, W2, W2th, W2tl);

  // scatter standalone (98 blocks x 1024 thr, ~5us, whole machine)
  bin_scatter_kernel<<<(E + 8191) / 8192, 1024, 0, stream>>>(ei, ew, gclaim, binned, E);

  // fused: bucket_build (196 blocks) ∥ gemm1 (391 blocks) — build hides under gemm
  const int NGEMM = (N + 127) / 128;
  fused_build_gemm1_kernel<<<NBUCK + NGEMM, 512, 0, stream>>>(
      x, W1th, xw, N, binned, gclaim, dinv, offs, cnts, edges);

  // layer 1 agg: h = bf16(relu(dinv*agg(xw) + b1))
  agg_kernel<HID_C, true, true><<<(N + 15) / 16, 256, 0, stream>>>(
      xw, offs, cnts, edges, dinv, b1, h, N);

  // layer 2: h2 = bf16(h @ W2)  [bf16-A GEMM, BM=256, N=64, 8 waves, Wh+Wl]
  gemm_bf16a_kernel<HID_C, OUT_C, 8, 1><<<(N + 255) / 256, 512, 0, stream>>>(h, W2th, W2tl, xw, N);
  agg_kernel<OUT_C, false, false><<<(N + 31) / 32, 256, 0, stream>>>(
      xw, offs, cnts, edges, dinv, b2, out, N);
}

// Round 23
// 102.568 us; speedup vs baseline: 1.0418x; 1.0418x over previous
//
#include <hip/hip_runtime.h>

#define NNODES 50000
#define NEDGES 800000
#define IN_C   512
#define HID_C  128
#define OUT_C  64
#define NBUCK  196        // bucket = dest >> 8
#define BCAP   5120       // fixed bucket capacity (mean 4096, sigma 64 -> +16 sigma)
#define BREG   5376       // padded CSR region per bucket (BCAP + 256 self-loops)

typedef float  f32x4  __attribute__((ext_vector_type(4)));
typedef __bf16 bf16x8 __attribute__((ext_vector_type(8)));
typedef short  short8 __attribute__((ext_vector_type(8)));

#define GLDS(src, dst) \
  __builtin_amdgcn_global_load_lds( \
      (const __attribute__((address_space(1))) unsigned int*)(src), \
      (__attribute__((address_space(3))) unsigned int*)(dst), 16, 0, 0)

__device__ __forceinline__ float bf2f(unsigned short u) {
  unsigned int x = (unsigned int)u << 16;
  return __builtin_bit_cast(float, x);
}
__device__ __forceinline__ unsigned short f16bits(float f) {
  _Float16 h = (_Float16)f;
  return __builtin_bit_cast(unsigned short, h);
}
__device__ __forceinline__ float f16val(unsigned short u) {
  return (float)__builtin_bit_cast(_Float16, u);
}

// ---------------- prep0: seed claim cursors + split/transpose W1,W2 ----------------

__device__ __forceinline__ void wsplit_one(const float* __restrict__ W,
                                           unsigned short* __restrict__ Th,
                                           unsigned short* __restrict__ Tl,
                                           int K, int N, int id) {
  int k = id % K, n = id / K;           // consecutive id -> consecutive k (coalesced writes)
  float f = W[(size_t)k * N + n];
  __bf16 hb = (__bf16)f;
  __bf16 lb = (__bf16)(f - (float)hb);
  Th[id] = __builtin_bit_cast(unsigned short, hb);
  Tl[id] = __builtin_bit_cast(unsigned short, lb);
}

__global__ void __launch_bounds__(256) prep0_kernel(
    unsigned int* __restrict__ gclaim,
    const float* __restrict__ W1, unsigned short* __restrict__ W1th,
    unsigned short* __restrict__ W1tl,
    const float* __restrict__ W2, unsigned short* __restrict__ W2th,
    unsigned short* __restrict__ W2tl) {
  int id = blockIdx.x * blockDim.x + threadIdx.x;
  if (id < 256) { if (id < NBUCK) gclaim[id] = (unsigned int)id * BCAP; return; }
  int s = id - 256;
  if (s < IN_C * HID_C) wsplit_one(W1, W1th, W1tl, IN_C, HID_C, s);
  else if (s < IN_C * HID_C + HID_C * OUT_C)
    wsplit_one(W2, W2th, W2tl, HID_C, OUT_C, s - IN_C * HID_C);
}

// ---------------- gemm1 body: Y = bf16( X @ bf16(W1) ), split-A 2-term ----------------
// Y ~= Xh@Wh + Xl@Wh = X@Wh (exact in X to ~2^-17; W quantized to bf16, rel 2^-9).
// 3 loads/stage/wave, LDS 48KB, 2 MFMA terms. 2-buffer dbuf LDS, one __syncthreads
// per K-chunk (r18/r19/r21/r22: deeper, wider, counted-vmcnt, build-fusion all
// neutral-to-worse — this is the measured optimum of the structure).
template <int K, int N, int WR, int WC>
__device__ __forceinline__ void gemm_body(const float* __restrict__ X,
                                          const unsigned short* __restrict__ Bth,
                                          unsigned short* __restrict__ Y, int M, int bid) {
  constexpr int NW = WR * WC;
  constexpr int BM = WR * 32;
  constexpr int NI = K / 32;
  constexpr int ASLOTS = (BM / 8) / NW;    // 2 (BM=128, NW=8)
  constexpr int BSLOTS = (N / 16) / NW;    // 1 (N=128, NW=8)

  __shared__ float          As[2][BM * 32];   // 2 x 16KB
  __shared__ unsigned short Bs[2][N * 32];    // 2 x 8KB

  int tid = threadIdx.x;
  int lane = tid & 63, wid = tid >> 6;
  int wr = wid / WC, wc = wid % WC;
  int row0blk = bid * BM;
  int row0 = row0blk + wr * 32;
  int rlo = lane & 15;
  int khi = lane >> 4;

  f32x4 acc[2][4] = {};

  auto stage = [&](int t, int buf) {
    int kb = t * 32;
#pragma unroll
    for (int i = 0; i < ASLOTS; ++i) {
      int slot = wid * ASLOTS + i;
      int rt = slot * 8 + (lane >> 3);
      int gr = row0blk + rt; gr = gr < M ? gr : M - 1;
      int gs = (lane & 7) ^ (lane >> 3);
      GLDS(X + (size_t)gr * K + kb + gs * 4, &As[buf][slot * 256]);
    }
#pragma unroll
    for (int i = 0; i < BSLOTS; ++i) {
      int slot = wid * BSLOTS + i;
      int c = slot * 16 + (lane >> 2);
      int gs = (lane & 3) ^ (lane >> 4);
      GLDS(Bth + (size_t)c * K + kb + gs * 8, &Bs[buf][slot * 512]);
    }
  };

  stage(0, 0);
  __syncthreads();

#pragma unroll 1
  for (int t = 0; t < NI; ++t) {
    int buf = t & 1;
    if (t + 1 < NI) stage(t + 1, buf ^ 1);

    bf16x8 ah[2], al[2];
#pragma unroll
    for (int m = 0; m < 2; ++m) {
      int rt = wr * 32 + m * 16 + rlo;
      int p0 = (khi * 2) ^ (rlo & 7), p1 = (khi * 2 + 1) ^ (rlo & 7);
      f32x4 v0 = *reinterpret_cast<const f32x4*>(&As[buf][rt * 32 + p0 * 4]);
      f32x4 v1 = *reinterpret_cast<const f32x4*>(&As[buf][rt * 32 + p1 * 4]);
      float f[8] = {v0.x, v0.y, v0.z, v0.w, v1.x, v1.y, v1.z, v1.w};
#pragma unroll
      for (int i = 0; i < 8; ++i) {
        __bf16 hv = (__bf16)f[i];
        ah[m][i] = hv;
        al[m][i] = (__bf16)(f[i] - (float)hv);
      }
    }
    short8 bh[4];
#pragma unroll
    for (int n = 0; n < 4; ++n) {
      int c = wc * 64 + n * 16 + rlo;
      int pos = khi ^ (rlo >> 2);
      bh[n] = *reinterpret_cast<const short8*>(&Bs[buf][c * 32 + pos * 8]);
    }
#pragma unroll
    for (int m = 0; m < 2; ++m)
#pragma unroll
      for (int n = 0; n < 4; ++n)
        acc[m][n] = __builtin_amdgcn_mfma_f32_16x16x32_bf16(
            ah[m], __builtin_bit_cast(bf16x8, bh[n]), acc[m][n], 0, 0, 0);
#pragma unroll
    for (int m = 0; m < 2; ++m)
#pragma unroll
      for (int n = 0; n < 4; ++n)
        acc[m][n] = __builtin_amdgcn_mfma_f32_16x16x32_bf16(
            al[m], __builtin_bit_cast(bf16x8, bh[n]), acc[m][n], 0, 0, 0);
    __syncthreads();
  }

  // C/D: col = lane&15, row = (lane>>4)*4 + reg; store bf16 (RNE)
#pragma unroll
  for (int m = 0; m < 2; ++m)
#pragma unroll
    for (int j = 0; j < 4; ++j) {
      int row = row0 + m * 16 + khi * 4 + j;
      if (row < M) {
#pragma unroll
        for (int n = 0; n < 4; ++n) {
          __bf16 q = (__bf16)acc[m][n][j];
          Y[(size_t)row * N + wc * 64 + n * 16 + rlo] = __builtin_bit_cast(unsigned short, q);
        }
      }
    }
}

// ---------------- fused: gemm1 (blocks [0,ngemm)) ∥ bin_scatter (rest) ----------------
// Best-measured configuration (r16/r20): gemm first, 512-thread blocks, BM=128.
// Record u64: src:16 | dest_lo:8 | f16(ew):16.
__global__ void __launch_bounds__(512, 4) fused_gemm1_scatter_kernel(
    const float* __restrict__ X, const unsigned short* __restrict__ Bth,
    unsigned short* __restrict__ Y, int M,
    int ngemm, const int* __restrict__ ei, const float* __restrict__ ew,
    unsigned int* __restrict__ gclaim, unsigned long long* __restrict__ binned, int nE) {
  if ((int)blockIdx.x < ngemm) {
    gemm_body<IN_C, HID_C, 4, 2>(X, Bth, Y, M, blockIdx.x);
    return;
  }
  __shared__ unsigned int h[NBUCK];
  __shared__ unsigned int cur[NBUCK];
  int t = threadIdx.x;
  if (t < NBUCK) h[t] = 0;
  __syncthreads();
  int base = ((int)blockIdx.x - ngemm) * 4096;
  int r[8]; unsigned int c[8]; unsigned short wb[8];
#pragma unroll
  for (int i = 0; i < 8; ++i) {
    int e = base + i * 512 + t;
    if (e < nE) {
      r[i] = ei[e];
      c[i] = (unsigned int)ei[nE + e];
      wb[i] = f16bits(ew[e]);
      atomicAdd(&h[c[i] >> 8], 1u);
    } else {
      c[i] = 0xFFFFFFFFu;
    }
  }
  __syncthreads();
  if (t < NBUCK) cur[t] = h[t] ? atomicAdd(&gclaim[t], h[t]) : 0u;
  __syncthreads();
#pragma unroll
  for (int i = 0; i < 8; ++i) {
    if (c[i] != 0xFFFFFFFFu) {
      unsigned int pos = atomicAdd(&cur[c[i] >> 8], 1u);
      unsigned long long rec = (unsigned long long)((unsigned int)r[i] & 0xFFFFu)
                             | ((unsigned long long)(c[i] & 0xFFu) << 16)
                             | ((unsigned long long)wb[i] << 32);
      binned[pos] = rec;
    }
  }
}

// ---------------- bucket_build: deg + CSR build, merged (dinv-fold) ----------------
__global__ void __launch_bounds__(256) bucket_build_kernel(
    const unsigned long long* __restrict__ binned, const unsigned int* __restrict__ gclaim,
    float* __restrict__ dinv, int* __restrict__ offs, unsigned short* __restrict__ cnts,
    unsigned int* __restrict__ edges) {
  int b = blockIdx.x, t = threadIdx.x;
  int base = b * BCAP;
  int cnt = (int)gclaim[b] - base;
  int nb = min(256, NNODES - b * 256);
  int csrbase = b * BREG;
  __shared__ unsigned int ec[256], wf[256], cur[256];
  __shared__ int sc[256];
  __shared__ unsigned int image[BREG];
  ec[t] = 0; wf[t] = 0;
  __syncthreads();
  for (int i = t; i < cnt; i += 256) {
    unsigned long long rec = binned[base + i];
    int dlo = (int)((rec >> 16) & 255ULL);
    atomicAdd(&ec[dlo], 1u);
    float w = f16val((unsigned short)(rec >> 32));
    atomicAdd(&wf[dlo], (unsigned int)(w * 1048576.0f + 0.5f));   // 2^20 fixed-point
  }
  __syncthreads();
  int cn = (t < nb) ? (int)ec[t] + 1 : 0;   // + self-loop slot
  sc[t] = cn;
  __syncthreads();
  for (int off = 1; off < 256; off <<= 1) {
    int u = (t >= off) ? sc[t - off] : 0;
    __syncthreads();
    sc[t] += u;
    __syncthreads();
  }
  if (t < nb) {
    float deg = (float)wf[t] * (1.0f / 1048576.0f) + 1.0f;   // + self-loop w=1
    int g = b * 256 + t;
    float di = rsqrtf(deg);
    dinv[g] = di;
    int loc = sc[t] - cn;
    offs[g] = csrbase + loc;
    cnts[g] = (unsigned short)ec[t];
    cur[t] = (unsigned int)(loc + 1);
    image[loc] = (unsigned int)g | (0x3C00u << 16);   // self-loop, w = f16(1.0)
  }
  __syncthreads();
  for (int i = t; i < cnt; i += 256) {
    unsigned long long rec = binned[base + i];
    int src = (int)(rec & 0xFFFFULL);
    int dlo = (int)((rec >> 16) & 255ULL);
    unsigned int wb = (unsigned int)((rec >> 32) & 0xFFFFULL);
    unsigned int pos = atomicAdd(&cur[dlo], 1u);
    image[pos] = (unsigned int)src | (wb << 16);
  }
  __syncthreads();
  int total = cnt + nb;
  for (int j = t; j < total; j += 256) edges[csrbase + j] = image[j];
}

// ---------------- bf16-A MFMA GEMM (layer 2): A bf16, 2 terms (Wh + Wl) ----------------
template <int K, int N, int WR, int WC>
__global__ void __launch_bounds__(WR * WC * 64, 4) gemm_bf16a_kernel(
    const unsigned short* __restrict__ X, const unsigned short* __restrict__ Bth,
    const unsigned short* __restrict__ Btl, unsigned short* __restrict__ Y, int M) {
  constexpr int NW = WR * WC;
  constexpr int BM = WR * 32;
  constexpr int NI = K / 32;
  constexpr int ASLOTS = (BM / 16) / NW;
  constexpr int BSLOTS = (N / 8) / NW;

  __shared__ unsigned short As[2][BM * 32];
  __shared__ unsigned short Bs[2][2][N * 32];

  int tid = threadIdx.x;
  int lane = tid & 63, wid = tid >> 6;
  int wr = wid / WC, wc = wid % WC;
  int row0blk = blockIdx.x * BM;
  int row0 = row0blk + wr * 32;
  int rlo = lane & 15;
  int khi = lane >> 4;

  f32x4 acc[2][4] = {};

  auto stage = [&](int t, int buf) {
    int kb = t * 32;
#pragma unroll
    for (int i = 0; i < ASLOTS; ++i) {
      int slot = wid * ASLOTS + i;
      int rt = slot * 16 + (lane >> 2);
      int gr = row0blk + rt; gr = gr < M ? gr : M - 1;
      int gs = (lane & 3) ^ ((lane >> 3) & 3);
      GLDS(X + (size_t)gr * K + kb + gs * 8, &As[buf][slot * 512]);
    }
#pragma unroll
    for (int i = 0; i < BSLOTS; ++i) {
      int slot = wid * BSLOTS + i;
      int half = slot / (N / 16);
      int idx = slot % (N / 16);
      const unsigned short* Wt = half ? Btl : Bth;
      int c = idx * 16 + (lane >> 2);
      int gs = (lane & 3) ^ (lane >> 4);
      GLDS(Wt + (size_t)c * K + kb + gs * 8, &Bs[buf][half][idx * 512]);
    }
  };

  stage(0, 0);
  __syncthreads();

#pragma unroll 1
  for (int t = 0; t < NI; ++t) {
    int buf = t & 1;
    if (t + 1 < NI) stage(t + 1, buf ^ 1);

    short8 ah[2];
#pragma unroll
    for (int m = 0; m < 2; ++m) {
      int rt = wr * 32 + m * 16 + rlo;
      int g = khi ^ ((rt >> 1) & 3);
      ah[m] = *reinterpret_cast<const short8*>(&As[buf][rt * 32 + g * 8]);
    }
    short8 bh[4], bl[4];
#pragma unroll
    for (int n = 0; n < 4; ++n) {
      int c = wc * 64 + n * 16 + rlo;
      int pos = khi ^ (rlo >> 2);
      bh[n] = *reinterpret_cast<const short8*>(&Bs[buf][0][c * 32 + pos * 8]);
      bl[n] = *reinterpret_cast<const short8*>(&Bs[buf][1][c * 32 + pos * 8]);
    }
#pragma unroll
    for (int m = 0; m < 2; ++m)
#pragma unroll
      for (int n = 0; n < 4; ++n)
        acc[m][n] = __builtin_amdgcn_mfma_f32_16x16x32_bf16(
            __builtin_bit_cast(bf16x8, ah[m]), __builtin_bit_cast(bf16x8, bh[n]),
            acc[m][n], 0, 0, 0);
#pragma unroll
    for (int m = 0; m < 2; ++m)
#pragma unroll
      for (int n = 0; n < 4; ++n)
        acc[m][n] = __builtin_amdgcn_mfma_f32_16x16x32_bf16(
            __builtin_bit_cast(bf16x8, ah[m]), __builtin_bit_cast(bf16x8, bl[n]),
            acc[m][n], 0, 0, 0);
    __syncthreads();
  }

#pragma unroll
  for (int m = 0; m < 2; ++m)
#pragma unroll
    for (int j = 0; j < 4; ++j) {
      int row = row0 + m * 16 + khi * 4 + j;
      if (row < M) {
#pragma unroll
        for (int n = 0; n < 4; ++n) {
          __bf16 q = (__bf16)acc[m][n][j];
          Y[(size_t)row * N + wc * 64 + n * 16 + rlo] = __builtin_bit_cast(unsigned short, q);
        }
      }
    }
}

// ---------------- CSR aggregation over bf16 features (dinv-folded) ----------------
template <int F, bool RELU, bool OUTBF>
__global__ void __launch_bounds__(256) agg_kernel(const unsigned short* __restrict__ feat,
                                                  const int* __restrict__ offs,
                                                  const unsigned short* __restrict__ cnts,
                                                  const unsigned int* __restrict__ edges,
                                                  const float* __restrict__ dinv,
                                                  const float* __restrict__ bias,
                                                  void* __restrict__ outv, int n) {
  constexpr int LPN = F / 8;
  constexpr int NPW = 64 / LPN;
  constexpr int NPB = 4 * NPW;
  int wid = threadIdx.x >> 6;
  int lane = threadIdx.x & 63;
  int node = blockIdx.x * NPB + wid * NPW + lane / LPN;
  int lf = (lane % LPN) * 8;
  if (node >= n) return;
  int e0 = offs[node];
  int e1 = e0 + 1 + (int)cnts[node];

  float acc[8] = {};

  auto fmaEdge = [&](unsigned int q) {
    int row = (int)(q & 0xFFFFu);
    float w = f16val((unsigned short)(q >> 16)) * dinv[row];
    short8 v = *reinterpret_cast<const short8*>(&feat[(size_t)row * F + lf]);
#pragma unroll
    for (int j = 0; j < 8; ++j)
      acc[j] = fmaf(w, bf2f((unsigned short)v[j]), acc[j]);
  };

  int e = e0;
  for (; e + 4 <= e1; e += 4) {
    unsigned int q0 = edges[e], q1 = edges[e + 1], q2 = edges[e + 2], q3 = edges[e + 3];
    fmaEdge(q0); fmaEdge(q1); fmaEdge(q2); fmaEdge(q3);
  }
  for (; e < e1; ++e) fmaEdge(edges[e]);

  float dd = dinv[node];
#pragma unroll
  for (int j = 0; j < 8; ++j) {
    acc[j] = fmaf(acc[j], dd, bias[lf + j]);
    if (RELU) acc[j] = fmaxf(acc[j], 0.f);
  }
  if constexpr (OUTBF) {
    short8 o;
#pragma unroll
    for (int j = 0; j < 8; ++j) {
      __bf16 q = (__bf16)acc[j];
      o[j] = (short)__builtin_bit_cast(unsigned short, q);
    }
    *reinterpret_cast<short8*>((unsigned short*)outv + (size_t)node * F + lf) = o;
  } else {
    float* out = (float*)outv;
    float4 o0 = make_float4(acc[0], acc[1], acc[2], acc[3]);
    float4 o1 = make_float4(acc[4], acc[5], acc[6], acc[7]);
    *reinterpret_cast<float4*>(&out[(size_t)node * F + lf]) = o0;
    *reinterpret_cast<float4*>(&out[(size_t)node * F + lf + 4]) = o1;
  }
}

// ---------------- launch ----------------

extern "C" void kernel_launch(void* const* d_in, const int* in_sizes, int n_in,
                              void* d_out, int out_size, void* d_ws, size_t ws_size,
                              hipStream_t stream) {
  const float* x  = (const float*)d_in[0];
  const int*   ei = (const int*)d_in[1];     // [2, E] int
  const float* ew = (const float*)d_in[2];
  const float* W1 = (const float*)d_in[3];
  const float* b1 = (const float*)d_in[4];
  const float* W2 = (const float*)d_in[5];
  const float* b2 = (const float*)d_in[6];
  float* out = (float*)d_out;

  const int N = NNODES, E = NEDGES;

  char* p = (char*)d_ws;
  auto alloc = [&](size_t bytes) { char* r = p; p += (bytes + 255) & ~(size_t)255; return r; };
  unsigned int* gclaim = (unsigned int*)alloc(256 * 4);
  float* dinv   = (float*)alloc((size_t)N * 4);
  int*   offs   = (int*)  alloc((size_t)N * 4);
  unsigned short* cnts = (unsigned short*)alloc((size_t)N * 2);
  unsigned long long* binned = (unsigned long long*)alloc((size_t)NBUCK * BCAP * 8);
  unsigned int* edges  = (unsigned int*)alloc((size_t)NBUCK * BREG * 4);
  unsigned short* xw = (unsigned short*)alloc((size_t)N * HID_C * 2); // bf16 pre-agg / h2
  unsigned short* h  = (unsigned short*)alloc((size_t)N * HID_C * 2); // bf16 layer-1 out
  unsigned short* W1th = (unsigned short*)alloc((size_t)IN_C * HID_C * 2);
  unsigned short* W1tl = (unsigned short*)alloc((size_t)IN_C * HID_C * 2);
  unsigned short* W2th = (unsigned short*)alloc((size_t)HID_C * OUT_C * 2);
  unsigned short* W2tl = (unsigned short*)alloc((size_t)HID_C * OUT_C * 2);

  // prep0: seed gclaim (bucket cursors) + wsplit W1,W2
  const int PREP0 = 256 + IN_C * HID_C + HID_C * OUT_C;
  prep0_kernel<<<(PREP0 + 255) / 256, 256, 0, stream>>>(
      gclaim, W1, W1th, W1tl, W2, W2th, W2tl);

  // fused: gemm1 (391 blocks, xw = bf16(x @ bf16(W1))) ∥ bin_scatter (196 blocks)
  const int NGEMM = (N + 127) / 128;
  const int NSCAT = (E + 4095) / 4096;
  fused_gemm1_scatter_kernel<<<NGEMM + NSCAT, 512, 0, stream>>>(
      x, W1th, xw, N, NGEMM, ei, ew, gclaim, binned, E);

  // merged deg + CSR build
  bucket_build_kernel<<<NBUCK, 256, 0, stream>>>(binned, gclaim, dinv, offs, cnts, edges);

  // layer 1 agg: h = bf16(relu(dinv*agg(xw) + b1))
  agg_kernel<HID_C, true, true><<<(N + 15) / 16, 256, 0, stream>>>(
      xw, offs, cnts, edges, dinv, b1, h, N);

  // layer 2: h2 = bf16(h @ W2)  [bf16-A GEMM, BM=256, N=64, 8 waves, Wh+Wl]
  gemm_bf16a_kernel<HID_C, OUT_C, 8, 1><<<(N + 255) / 256, 512, 0, stream>>>(h, W2th, W2tl, xw, N);
  agg_kernel<OUT_C, false, false><<<(N + 31) / 32, 256, 0, stream>>>(
      xw, offs, cnts, edges, dinv, b2, out, N);
}